// Round 7
// baseline (254.597 us; speedup 1.0000x reference)
//
#include <hip/hip_runtime.h>

// Spatial transformer: trilinear warp of src by flow, border padding.
// D=160, H=192, W=160.  u = (idx + flow) * S/(S-1) - 0.5, clamp, trilinear.
//
// Lineage:
//   R5-R9: global-gather designs all ~50us => scattered-line service wall.
//   R10: LDS-staged 32^3 bf16 window per 16^3 tile -> 52us; latency-bound
//        (flow loads exposed mid-kernel; ~73% of wave-voxel-iters serialize
//        a ~900cyc global slow-path chain).
//   R11: bundled fix REGRESSED (124us): launch_bounds(1024,8) forced
//        VGPR 52->32, destroying per-wave MLP (VALU 7%, hbm 0.94TB/s,
//        occupancy 63% -- TLP can't replace ILP).
//   R12 (this kernel, resubmitted after infra-only container failure):
//   R10 shape (512 thr, no min-wave cap). Only two changes:
//   (1) outliers -> atomic list + separate fixup kernel (no in-wave scatter)
//   (2) 8 voxels/thread, ALL flow loaded before the barrier (latency hides
//       under staging).

#define DD 160
#define HH 192
#define WW 160
#define DHW (DD * HH * WW)
#define PW 192                                   /* padded width: slot s <-> gx = clamp(s-8) */
#define NROWS (DD * HH)                          /* 30720 */
#define BSRC_BYTES ((size_t)NROWS * PW * 2)      /* 11,796,480 */
#define CAP_OUT (1u << 19)                       /* 524288 list slots; expect ~100K */
#define CNT_OFF BSRC_BYTES
#define LIST_OFF (BSRC_BYTES + 64)
#define WS_NEEDED (LIST_OFF + 4ULL * CAP_OUT)

__device__ __forceinline__ unsigned short bf16_rn(float f) {
    unsigned int u = __float_as_uint(f);
    return (unsigned short)((u + 0x7FFFu + ((u >> 16) & 1u)) >> 16);
}

// ---------------- prepass: padded bf16 volume (+ zero outlier counter) ----------------
// bsrc[row][s] = bf16(src[row][clamp(s-8, 0, WW-1)]), s in [0,192)
__global__ __launch_bounds__(256) void pack_bf16_kernel(
    const float* __restrict__ src, unsigned short* __restrict__ bsrc,
    unsigned int* __restrict__ cnt)
{
    if (blockIdx.x == 0 && threadIdx.x == 0) *cnt = 0u;   // reset each replay

    int t = blockIdx.x * 256 + (int)threadIdx.x;  // 737,280 threads = 2880 blocks
    int q = t % (PW / 8);                          // 24 chunks of 8 slots
    int row = t / (PW / 8);                        // [0, 30720)
    const float* srow = src + (size_t)row * WW;
    int j0 = q * 8;

    unsigned int e[4];
    #pragma unroll
    for (int i = 0; i < 4; ++i) {
        int ga = min(max(j0 + 2 * i     - 8, 0), WW - 1);
        int gb = min(max(j0 + 2 * i + 1 - 8, 0), WW - 1);
        e[i] = (unsigned int)bf16_rn(srow[ga]) | ((unsigned int)bf16_rn(srow[gb]) << 16);
    }
    *(uint4*)(bsrc + (size_t)row * PW + j0) = make_uint4(e[0], e[1], e[2], e[3]);
}

// ---------------- main: LDS-staged trilinear, outliers deferred ----------------
__global__ __launch_bounds__(512) void warp_lds_kernel(
    const unsigned short* __restrict__ bsrc,
    const float* __restrict__ flow,
    float* __restrict__ out,
    unsigned int* __restrict__ cnt,
    unsigned int* __restrict__ list)
{
    __shared__ unsigned short sm[32 * 32 * 32];   // 64 KB: [dz][dy][dx]

    int tile = blockIdx.x;                        // grid 1200 = 10 x 12 x 10
    int txq = tile % 10;
    int rem = tile / 10;
    int tyq = rem % 12;
    int tzq = rem / 12;
    int bx = txq * 16, by = tyq * 16, bz = tzq * 16;

    int t = (int)threadIdx.x;                     // 512 threads = 8 waves
    int lane = t & 63;
    int wave = t >> 6;

    // ---- stage window: rows [b-8, b+24) in z,y; x slots [bx, bx+32) ----
    // instr j stages 16 rows x 64B (lane L: row j*16+L/4, 16B chunk L%4);
    // 8 instrs per wave, conflict-free ds_write_b128.
    #pragma unroll
    for (int k = 0; k < 8; ++k) {
        int row = (wave * 8 + k) * 16 + (lane >> 2);   // 0..1023 = zz*32+yy
        int zz = row >> 5;
        int yy = row & 31;
        int gz = min(max(bz - 8 + zz, 0), DD - 1);
        int gy = min(max(by - 8 + yy, 0), HH - 1);
        const uint4 vv = *(const uint4*)(bsrc + (size_t)(gz * HH + gy) * PW + bx + (lane & 3) * 8);
        *(uint4*)&sm[row * 32 + (lane & 3) * 8] = vv;
    }

    // ---- ALL flow for this thread's 8 voxels, issued BEFORE the barrier ----
    int vi = t * 8;                               // tile-linear voxel index
    int tx = vi & 15;                             // 0 or 8: 8 consecutive x
    int ty = (vi >> 4) & 15;
    int tz = vi >> 8;
    int gw = bx + tx, gh = by + ty, gd = bz + tz;
    int gbase = (gd * HH + gh) * WW + gw;

    const float4 fza = *(const float4*)(flow + gbase);
    const float4 fzb = *(const float4*)(flow + gbase + 4);
    const float4 fya = *(const float4*)(flow + DHW + gbase);
    const float4 fyb = *(const float4*)(flow + DHW + gbase + 4);
    const float4 fxa = *(const float4*)(flow + 2 * DHW + gbase);
    const float4 fxb = *(const float4*)(flow + 2 * DHW + gbase + 4);
    const float* pz[2] = { (const float*)&fza, (const float*)&fzb };
    const float* py[2] = { (const float*)&fya, (const float*)&fyb };
    const float* px[2] = { (const float*)&fxa, (const float*)&fxb };

    __syncthreads();

    const float SX = (float)WW / (float)(WW - 1);
    const float SY = (float)HH / (float)(HH - 1);
    const float SZ = (float)DD / (float)(DD - 1);

    float res[8];
    #pragma unroll
    for (int v = 0; v < 8; ++v) {
        float ux = fmaf((float)(gw + v) + px[v >> 2][v & 3], SX, -0.5f);
        float uy = fmaf((float)gh + py[v >> 2][v & 3],       SY, -0.5f);
        float uz = fmaf((float)gd + pz[v >> 2][v & 3],       SZ, -0.5f);
        ux = fminf(fmaxf(ux, 0.0f), (float)(WW - 1));
        uy = fminf(fmaxf(uy, 0.0f), (float)(HH - 1));
        uz = fminf(fmaxf(uz, 0.0f), (float)(DD - 1));
        float x0f = floorf(ux), y0f = floorf(uy), z0f = floorf(uz);
        float wx = ux - x0f, wy = uy - y0f, wz = uz - z0f;
        int x0 = (int)x0f, y0 = (int)y0f, z0 = (int)z0f;

        int dx = x0 - bx + 8;                 // window-local coords
        int dy = y0 - by + 8;
        int dz = z0 - bz + 8;
        bool ok = ((unsigned)dx <= 30u) & ((unsigned)dy <= 30u) & ((unsigned)dz <= 30u);

        if (!ok) {
            // defer: record voxel id; fixup kernel overwrites out[id].
            unsigned int slot = atomicAdd(cnt, 1u);   // wave-coalesced by compiler
            if (slot < CAP_OUT) list[slot] = (unsigned int)(gbase + v);
            // clamp so the LDS taps stay in bounds (finite garbage, fixed up).
            dx = min(max(dx, 0), 30);
            dy = min(max(dy, 0), 30);
            dz = min(max(dz, 0), 30);
        }

        int idx = dz * 1024 + dy * 32 + dx;   // max 30*1024+30*32+30+1057 = 32767
        float c000 = __uint_as_float((unsigned)sm[idx       ] << 16);
        float c001 = __uint_as_float((unsigned)sm[idx + 1   ] << 16);
        float c010 = __uint_as_float((unsigned)sm[idx + 32  ] << 16);
        float c011 = __uint_as_float((unsigned)sm[idx + 33  ] << 16);
        float c100 = __uint_as_float((unsigned)sm[idx + 1024] << 16);
        float c101 = __uint_as_float((unsigned)sm[idx + 1025] << 16);
        float c110 = __uint_as_float((unsigned)sm[idx + 1056] << 16);
        float c111 = __uint_as_float((unsigned)sm[idx + 1057] << 16);
        float r00 = fmaf(wx, c001 - c000, c000);
        float r01 = fmaf(wx, c011 - c010, c010);
        float r10 = fmaf(wx, c101 - c100, c100);
        float r11 = fmaf(wx, c111 - c110, c110);
        float r0  = fmaf(wy, r01 - r00, r00);
        float r1  = fmaf(wy, r11 - r10, r10);
        res[v] = fmaf(wz, r1 - r0, r0);
    }
    *(float4*)(out + gbase)     = make_float4(res[0], res[1], res[2], res[3]);
    *(float4*)(out + gbase + 4) = make_float4(res[4], res[5], res[6], res[7]);
}

// ---------------- fixup: exact f32 border gather for listed outliers ----------------
struct __align__(4) F2 { float a, b; };

__global__ __launch_bounds__(256) void fixup_kernel(
    const float* __restrict__ src,
    const float* __restrict__ flow,
    float* __restrict__ out,
    const unsigned int* __restrict__ cnt,
    const unsigned int* __restrict__ list)
{
    unsigned int n = min(*cnt, CAP_OUT);
    const float SX = (float)WW / (float)(WW - 1);
    const float SY = (float)HH / (float)(HH - 1);
    const float SZ = (float)DD / (float)(DD - 1);

    for (unsigned int t = blockIdx.x * 256 + threadIdx.x; t < n; t += 512 * 256) {
        int id = (int)list[t];
        int w = id % WW;
        int tmp = id / WW;
        int h = tmp % HH;
        int d = tmp / HH;

        float flz = flow[id];
        float fly = flow[DHW + id];
        float flx = flow[2 * DHW + id];

        float ux = fmaf((float)w + flx, SX, -0.5f);
        float uy = fmaf((float)h + fly, SY, -0.5f);
        float uz = fmaf((float)d + flz, SZ, -0.5f);
        ux = fminf(fmaxf(ux, 0.0f), (float)(WW - 1));
        uy = fminf(fmaxf(uy, 0.0f), (float)(HH - 1));
        uz = fminf(fmaxf(uz, 0.0f), (float)(DD - 1));
        float x0f = floorf(ux), y0f = floorf(uy), z0f = floorf(uz);
        float fx = ux - x0f, fy = uy - y0f, fz = uz - z0f;
        int x0 = (int)x0f, y0 = (int)y0f, z0 = (int)z0f;
        int y1 = min(y0 + 1, HH - 1);
        int z1 = min(z0 + 1, DD - 1);
        int xb = min(x0, WW - 2);
        bool xe = (x0 == WW - 1);
        F2 q00 = *(const F2*)(src + ((size_t)z0 * HH + y0) * WW + xb);
        F2 q01 = *(const F2*)(src + ((size_t)z0 * HH + y1) * WW + xb);
        F2 q10 = *(const F2*)(src + ((size_t)z1 * HH + y0) * WW + xb);
        F2 q11 = *(const F2*)(src + ((size_t)z1 * HH + y1) * WW + xb);
        float c000 = xe ? q00.b : q00.a, c001 = q00.b;
        float c010 = xe ? q01.b : q01.a, c011 = q01.b;
        float c100 = xe ? q10.b : q10.a, c101 = q10.b;
        float c110 = xe ? q11.b : q11.a, c111 = q11.b;
        float r00 = fmaf(fx, c001 - c000, c000);
        float r01 = fmaf(fx, c011 - c010, c010);
        float r10 = fmaf(fx, c101 - c100, c100);
        float r11 = fmaf(fx, c111 - c110, c110);
        float r0  = fmaf(fy, r01 - r00, r00);
        float r1  = fmaf(fy, r11 - r10, r10);
        out[id] = fmaf(fz, r1 - r0, r0);
    }
}

// ---------------- fallback (proven R2 kernel) if ws too small ----------------
__global__ __launch_bounds__(256) void warp_direct_kernel(
    const float* __restrict__ src,
    const float* __restrict__ flow,
    float* __restrict__ out)
{
    int b = blockIdx.x;
    int nb = (b & 7) * 600 + (b >> 3);
    int base = (nb * 256 + (int)threadIdx.x) * 4;

    int w = base % WW;
    int tmp = base / WW;
    int h = tmp % HH;
    int d = tmp / HH;

    const float4 f0  = *(const float4*)(flow + base);
    const float4 f1  = *(const float4*)(flow + DHW + base);
    const float4 f2v = *(const float4*)(flow + 2 * DHW + base);
    const float* f0p = (const float*)&f0;
    const float* f1p = (const float*)&f1;
    const float* f2p = (const float*)&f2v;

    const float SX = (float)WW / (float)(WW - 1);
    const float SY = (float)HH / (float)(HH - 1);
    const float SZ = (float)DD / (float)(DD - 1);

    float res[4];
    #pragma unroll
    for (int v = 0; v < 4; ++v) {
        float ux = fmaf((float)(w + v) + f2p[v], SX, -0.5f);
        float uy = fmaf((float)h + f1p[v],       SY, -0.5f);
        float uz = fmaf((float)d + f0p[v],       SZ, -0.5f);
        ux = fminf(fmaxf(ux, 0.0f), (float)(WW - 1));
        uy = fminf(fmaxf(uy, 0.0f), (float)(HH - 1));
        uz = fminf(fmaxf(uz, 0.0f), (float)(DD - 1));
        float x0f = floorf(ux), y0f = floorf(uy), z0f = floorf(uz);
        float fx = ux - x0f, fy = uy - y0f, fz = uz - z0f;
        int x0 = (int)x0f, y0 = (int)y0f, z0 = (int)z0f;
        int y1 = min(y0 + 1, HH - 1);
        int z1 = min(z0 + 1, DD - 1);
        int xb = min(x0, WW - 2);
        bool xe = (x0 == WW - 1);
        F2 q00 = *(const F2*)(src + ((size_t)z0 * HH + y0) * WW + xb);
        F2 q01 = *(const F2*)(src + ((size_t)z0 * HH + y1) * WW + xb);
        F2 q10 = *(const F2*)(src + ((size_t)z1 * HH + y0) * WW + xb);
        F2 q11 = *(const F2*)(src + ((size_t)z1 * HH + y1) * WW + xb);
        float c000 = xe ? q00.b : q00.a, c001 = q00.b;
        float c010 = xe ? q01.b : q01.a, c011 = q01.b;
        float c100 = xe ? q10.b : q10.a, c101 = q10.b;
        float c110 = xe ? q11.b : q11.a, c111 = q11.b;
        float r00 = fmaf(fx, c001 - c000, c000);
        float r01 = fmaf(fx, c011 - c010, c010);
        float r10 = fmaf(fx, c101 - c100, c100);
        float r11 = fmaf(fx, c111 - c110, c110);
        float r0  = fmaf(fy, r01 - r00, r00);
        float r1  = fmaf(fy, r11 - r10, r10);
        res[v]    = fmaf(fz, r1 - r0, r0);
    }
    *(float4*)(out + base) = make_float4(res[0], res[1], res[2], res[3]);
}

extern "C" void kernel_launch(void* const* d_in, const int* in_sizes, int n_in,
                              void* d_out, int out_size, void* d_ws, size_t ws_size,
                              hipStream_t stream) {
    const float* src  = (const float*)d_in[0];   // [1,1,D,H,W]
    const float* flow = (const float*)d_in[1];   // [1,3,D,H,W]
    // d_in[2] identity grid: unused (recomputed)
    float* out = (float*)d_out;

    if (ws_size >= WS_NEEDED) {
        unsigned short* bsrc = (unsigned short*)d_ws;
        unsigned int* cnt  = (unsigned int*)((char*)d_ws + CNT_OFF);
        unsigned int* list = (unsigned int*)((char*)d_ws + LIST_OFF);
        pack_bf16_kernel<<<(NROWS * (PW / 8)) / 256, 256, 0, stream>>>(src, bsrc, cnt);
        warp_lds_kernel<<<1200, 512, 0, stream>>>(bsrc, flow, out, cnt, list);
        fixup_kernel<<<512, 256, 0, stream>>>(src, flow, out, cnt, list);
    } else {
        warp_direct_kernel<<<DHW / 4 / 256, 256, 0, stream>>>(src, flow, out);
    }
}

// Round 8
// 172.833 us; speedup vs baseline: 1.4731x; 1.4731x over previous
//
#include <hip/hip_runtime.h>

// Spatial transformer: trilinear warp of src by flow, border padding.
// D=160, H=192, W=160.  u = (idx + flow) * S/(S-1) - 0.5, clamp, trilinear.
//
// Lineage:
//   R5-R9: global-gather designs all ~50us (scattered-line service wall).
//   R10: LDS-staged 32^3 bf16 window / 16^3 tile -> 52us. Traffic only
//        explains ~19us; rest = latency stalls at 29% occupancy (64KB LDS
//        -> 2 blocks/CU -> 50% cap, plus tail).
//   R11/R12: outlier deferral via per-voxel global atomicAdd w/ return dep
//        -> BOTH 124us regardless of occupancy (29% vs 63%): same-address
//        device atomic = chip-wide serializer. NEVER on the per-element path.
// R13: no atomics, no fixup (R10's proven in-wave slow path stays).
//   (1) tile 16x16x8, window 32x32x24 = 48KB LDS -> 3 blocks/CU (75% cap)
//   (2) single pass, flow hoisted before the barrier
//   bsrc (11.8MB) is L3-resident so extra staging re-reads are L3, not HBM.

#define DD 160
#define HH 192
#define WW 160
#define DHW (DD * HH * WW)
#define PW 192                                   /* padded width: slot s <-> gx = clamp(s-8) */
#define NROWS (DD * HH)                          /* 30720 */
#define WS_NEEDED ((size_t)NROWS * PW * 2)       /* 11,796,480 B */

__device__ __forceinline__ unsigned short bf16_rn(float f) {
    unsigned int u = __float_as_uint(f);
    return (unsigned short)((u + 0x7FFFu + ((u >> 16) & 1u)) >> 16);
}

// ---------------- prepass: padded bf16 volume ----------------
// bsrc[row][s] = bf16(src[row][clamp(s-8, 0, WW-1)]), s in [0,192)
__global__ __launch_bounds__(256) void pack_bf16_kernel(
    const float* __restrict__ src, unsigned short* __restrict__ bsrc)
{
    int t = blockIdx.x * 256 + (int)threadIdx.x;  // 737,280 threads = 2880 blocks
    int q = t % (PW / 8);                          // 24 chunks of 8 slots
    int row = t / (PW / 8);                        // [0, 30720)
    const float* srow = src + (size_t)row * WW;
    int j0 = q * 8;

    unsigned int e[4];
    #pragma unroll
    for (int i = 0; i < 4; ++i) {
        int ga = min(max(j0 + 2 * i     - 8, 0), WW - 1);
        int gb = min(max(j0 + 2 * i + 1 - 8, 0), WW - 1);
        e[i] = (unsigned int)bf16_rn(srow[ga]) | ((unsigned int)bf16_rn(srow[gb]) << 16);
    }
    *(uint4*)(bsrc + (size_t)row * PW + j0) = make_uint4(e[0], e[1], e[2], e[3]);
}

// ---------------- main: LDS-staged trilinear, 48KB window ----------------
struct __align__(4) F2 { float a, b; };

__global__ __launch_bounds__(512) void warp_lds_kernel(
    const unsigned short* __restrict__ bsrc,
    const float* __restrict__ src,
    const float* __restrict__ flow,
    float* __restrict__ out)
{
    __shared__ unsigned short sm[24 * 32 * 32];   // 48 KB: [dz<24][dy<32][dx<32]

    // grid 2400 = 10 x 12 x 20; XCD k gets contiguous nb range (bsrc slab
    // ~1.5MB -> L2-warm per XCD).
    int b = blockIdx.x;
    int nb = (b & 7) * 300 + (b >> 3);
    int txq = nb % 10;
    int rem = nb / 10;
    int tyq = rem % 12;
    int tzq = rem / 12;                           // [0,20)
    int bx = txq * 16, by = tyq * 16, bz = tzq * 8;

    int t = (int)threadIdx.x;                     // 512 threads = 8 waves
    int lane = t & 63;
    int wave = t >> 6;

    // ---- stage window: z in [bz-8, bz+16), y in [by-8, by+24), x slots [bx,bx+32) ----
    // 768 rows x 64B; wave w stages rows [w*96, w*96+96) in 6 instrs of
    // 16 rows (lane L: row +L/4, 16B chunk L%4). Conflict-free ds_write_b128.
    #pragma unroll
    for (int k = 0; k < 6; ++k) {
        int row = (wave * 6 + k) * 16 + (lane >> 2);   // 0..767 = zz*32+yy
        int zz = row >> 5;                              // [0,24)
        int yy = row & 31;
        int gz = min(max(bz - 8 + zz, 0), DD - 1);
        int gy = min(max(by - 8 + yy, 0), HH - 1);
        const uint4 vv = *(const uint4*)(bsrc + (size_t)(gz * HH + gy) * PW + bx + (lane & 3) * 8);
        *(uint4*)&sm[row * 32 + (lane & 3) * 8] = vv;
    }

    // ---- flow for this thread's 4 voxels, issued BEFORE the barrier ----
    int vi = t * 4;                               // [0,2048) = 16x16x8 tile
    int tx = vi & 15;
    int ty = (vi >> 4) & 15;
    int tz = vi >> 8;                             // [0,8)
    int gw = bx + tx, gh = by + ty, gd = bz + tz;
    int gbase = (gd * HH + gh) * WW + gw;

    const float4 fz4 = *(const float4*)(flow + gbase);            // -> D/z
    const float4 fy4 = *(const float4*)(flow + DHW + gbase);      // -> H/y
    const float4 fx4 = *(const float4*)(flow + 2 * DHW + gbase);  // -> W/x
    const float* pz = (const float*)&fz4;
    const float* py = (const float*)&fy4;
    const float* px = (const float*)&fx4;

    __syncthreads();

    const float SX = (float)WW / (float)(WW - 1);
    const float SY = (float)HH / (float)(HH - 1);
    const float SZ = (float)DD / (float)(DD - 1);

    float res[4];
    #pragma unroll
    for (int v = 0; v < 4; ++v) {
        float ux = fmaf((float)(gw + v) + px[v], SX, -0.5f);
        float uy = fmaf((float)gh + py[v],       SY, -0.5f);
        float uz = fmaf((float)gd + pz[v],       SZ, -0.5f);
        ux = fminf(fmaxf(ux, 0.0f), (float)(WW - 1));
        uy = fminf(fmaxf(uy, 0.0f), (float)(HH - 1));
        uz = fminf(fmaxf(uz, 0.0f), (float)(DD - 1));
        float x0f = floorf(ux), y0f = floorf(uy), z0f = floorf(uz);
        float wx = ux - x0f, wy = uy - y0f, wz = uz - z0f;
        int x0 = (int)x0f, y0 = (int)y0f, z0 = (int)z0f;

        int dx = x0 - bx + 8;                 // window-local coords
        int dy = y0 - by + 8;
        int dz = z0 - bz + 8;
        // need [d, d+1] in window: dx,dy <= 30; dz <= 22
        bool ok = ((unsigned)dx <= 30u) & ((unsigned)dy <= 30u) & ((unsigned)dz <= 22u);

        float r;
        if (ok) {
            int idx = dz * 1024 + dy * 32 + dx;   // max 23518; +1057 = 24575 < 24576
            float c000 = __uint_as_float((unsigned)sm[idx       ] << 16);
            float c001 = __uint_as_float((unsigned)sm[idx + 1   ] << 16);
            float c010 = __uint_as_float((unsigned)sm[idx + 32  ] << 16);
            float c011 = __uint_as_float((unsigned)sm[idx + 33  ] << 16);
            float c100 = __uint_as_float((unsigned)sm[idx + 1024] << 16);
            float c101 = __uint_as_float((unsigned)sm[idx + 1025] << 16);
            float c110 = __uint_as_float((unsigned)sm[idx + 1056] << 16);
            float c111 = __uint_as_float((unsigned)sm[idx + 1057] << 16);
            float r00 = fmaf(wx, c001 - c000, c000);
            float r01 = fmaf(wx, c011 - c010, c010);
            float r10 = fmaf(wx, c101 - c100, c100);
            float r11 = fmaf(wx, c111 - c110, c110);
            float r0  = fmaf(wy, r01 - r00, r00);
            float r1  = fmaf(wy, r11 - r10, r10);
            r = fmaf(wz, r1 - r0, r0);
        } else {
            // slow path (~2% of voxels): proven border-clamped f32 gather
            int y1 = min(y0 + 1, HH - 1);
            int z1 = min(z0 + 1, DD - 1);
            int xb = min(x0, WW - 2);
            bool xe = (x0 == WW - 1);
            F2 q00 = *(const F2*)(src + ((size_t)z0 * HH + y0) * WW + xb);
            F2 q01 = *(const F2*)(src + ((size_t)z0 * HH + y1) * WW + xb);
            F2 q10 = *(const F2*)(src + ((size_t)z1 * HH + y0) * WW + xb);
            F2 q11 = *(const F2*)(src + ((size_t)z1 * HH + y1) * WW + xb);
            float c000 = xe ? q00.b : q00.a, c001 = q00.b;
            float c010 = xe ? q01.b : q01.a, c011 = q01.b;
            float c100 = xe ? q10.b : q10.a, c101 = q10.b;
            float c110 = xe ? q11.b : q11.a, c111 = q11.b;
            float r00 = fmaf(wx, c001 - c000, c000);
            float r01 = fmaf(wx, c011 - c010, c010);
            float r10 = fmaf(wx, c101 - c100, c100);
            float r11 = fmaf(wx, c111 - c110, c110);
            float r0  = fmaf(wy, r01 - r00, r00);
            float r1  = fmaf(wy, r11 - r10, r10);
            r = fmaf(wz, r1 - r0, r0);
        }
        res[v] = r;
    }
    *(float4*)(out + gbase) = make_float4(res[0], res[1], res[2], res[3]);
}

// ---------------- fallback (proven R2 kernel) if ws too small ----------------
__global__ __launch_bounds__(256) void warp_direct_kernel(
    const float* __restrict__ src,
    const float* __restrict__ flow,
    float* __restrict__ out)
{
    int b = blockIdx.x;
    int nb = (b & 7) * 600 + (b >> 3);
    int base = (nb * 256 + (int)threadIdx.x) * 4;

    int w = base % WW;
    int tmp = base / WW;
    int h = tmp % HH;
    int d = tmp / HH;

    const float4 f0  = *(const float4*)(flow + base);
    const float4 f1  = *(const float4*)(flow + DHW + base);
    const float4 f2v = *(const float4*)(flow + 2 * DHW + base);
    const float* f0p = (const float*)&f0;
    const float* f1p = (const float*)&f1;
    const float* f2p = (const float*)&f2v;

    const float SX = (float)WW / (float)(WW - 1);
    const float SY = (float)HH / (float)(HH - 1);
    const float SZ = (float)DD / (float)(DD - 1);

    float res[4];
    #pragma unroll
    for (int v = 0; v < 4; ++v) {
        float ux = fmaf((float)(w + v) + f2p[v], SX, -0.5f);
        float uy = fmaf((float)h + f1p[v],       SY, -0.5f);
        float uz = fmaf((float)d + f0p[v],       SZ, -0.5f);
        ux = fminf(fmaxf(ux, 0.0f), (float)(WW - 1));
        uy = fminf(fmaxf(uy, 0.0f), (float)(HH - 1));
        uz = fminf(fmaxf(uz, 0.0f), (float)(DD - 1));
        float x0f = floorf(ux), y0f = floorf(uy), z0f = floorf(uz);
        float fx = ux - x0f, fy = uy - y0f, fz = uz - z0f;
        int x0 = (int)x0f, y0 = (int)y0f, z0 = (int)z0f;
        int y1 = min(y0 + 1, HH - 1);
        int z1 = min(z0 + 1, DD - 1);
        int xb = min(x0, WW - 2);
        bool xe = (x0 == WW - 1);
        F2 q00 = *(const F2*)(src + ((size_t)z0 * HH + y0) * WW + xb);
        F2 q01 = *(const F2*)(src + ((size_t)z0 * HH + y1) * WW + xb);
        F2 q10 = *(const F2*)(src + ((size_t)z1 * HH + y0) * WW + xb);
        F2 q11 = *(const F2*)(src + ((size_t)z1 * HH + y1) * WW + xb);
        float c000 = xe ? q00.b : q00.a, c001 = q00.b;
        float c010 = xe ? q01.b : q01.a, c011 = q01.b;
        float c100 = xe ? q10.b : q10.a, c101 = q10.b;
        float c110 = xe ? q11.b : q11.a, c111 = q11.b;
        float r00 = fmaf(fx, c001 - c000, c000);
        float r01 = fmaf(fx, c011 - c010, c010);
        float r10 = fmaf(fx, c101 - c100, c100);
        float r11 = fmaf(fx, c111 - c110, c110);
        float r0  = fmaf(fy, r01 - r00, r00);
        float r1  = fmaf(fy, r11 - r10, r10);
        res[v]    = fmaf(fz, r1 - r0, r0);
    }
    *(float4*)(out + base) = make_float4(res[0], res[1], res[2], res[3]);
}

extern "C" void kernel_launch(void* const* d_in, const int* in_sizes, int n_in,
                              void* d_out, int out_size, void* d_ws, size_t ws_size,
                              hipStream_t stream) {
    const float* src  = (const float*)d_in[0];   // [1,1,D,H,W]
    const float* flow = (const float*)d_in[1];   // [1,3,D,H,W]
    // d_in[2] identity grid: unused (recomputed)
    float* out = (float*)d_out;

    if (ws_size >= WS_NEEDED) {
        unsigned short* bsrc = (unsigned short*)d_ws;
        pack_bf16_kernel<<<(NROWS * (PW / 8)) / 256, 256, 0, stream>>>(src, bsrc);
        warp_lds_kernel<<<2400, 512, 0, stream>>>(bsrc, src, flow, out);
    } else {
        warp_direct_kernel<<<DHW / 4 / 256, 256, 0, stream>>>(src, flow, out);
    }
}